// Round 1
// baseline (619.469 us; speedup 1.0000x reference)
//
#include <hip/hip_runtime.h>
#include <hip/hip_bf16.h>

// ---------------- problem constants ----------------
#define BB 8
#define SS 2000
#define IN_CH 120
#define GRID_CH 64
#define NPTS 10000
#define IC 512
#define DIRS 4
#define CATCH 248
#define CATPAD 256
#define NLAY 6
#define MROWS 16000          // B*S
#define MROWS4 64000         // B*S*DIRS

typedef __bf16 bf16x8 __attribute__((ext_vector_type(8)));
typedef float f32x4 __attribute__((ext_vector_type(4)));

#define DEVI __device__ __forceinline__

DEVI unsigned short f2bf(float f) {
    __hip_bfloat16 h = __float2bfloat16(f);
    return __builtin_bit_cast(unsigned short, h);
}
DEVI float bf2f(unsigned short u) {
    unsigned int x = ((unsigned int)u) << 16;
    return __builtin_bit_cast(float, x);
}
DEVI float leaky(float x) { return x > 0.f ? x : 0.1f * x; }

DEVI void gload16(const void* g, void* l) {
    __builtin_amdgcn_global_load_lds(
        (const unsigned int __attribute__((address_space(1)))*)g,
        (unsigned int __attribute__((address_space(3)))*)l, 16, 0, 0);
}

// ---------------- workspace layout (bytes) ----------------
// all 256B-aligned
static const size_t OFF_FEATS  = 0;            // 8*128 f32            = 4096
static const size_t OFF_PROJWT = 4096;         // 512*256 bf16         = 262144
static const size_t OFF_RES0WT = 266240;       // 512*256 bf16
static const size_t OFF_RES1WT = 528384;       // 512*512 bf16         = 524288
static const size_t OFF_LAYWT  = 1052672;      // 6*512*512 bf16       = 3145728
static const size_t OFF_MYIN   = 4198400;      // 16000*256 bf16       = 8192000
static const size_t OFF_R0     = 12390400;     // 16000*512 bf16       = 16384000
static const size_t OFF_R      = 28774400;     // 16000*512 bf16
static const size_t OFF_A0     = 45158400;     // 64000*512 bf16       = 65536000
static const size_t OFF_A1     = 110694400;    // 64000*512 bf16  (end 176230400)

// ---------------- weight convert: f32 [L][K][N] -> bf16 [L][N][Kpad] (transposed, pad K) ----
__global__ void wconv_k(const float* __restrict__ src, unsigned short* __restrict__ dst,
                        int K, int Kpad, int N, int total) {
    int idx = blockIdx.x * 256 + threadIdx.x;
    if (idx >= total) return;
    int k = idx % Kpad;
    int rem = idx / Kpad;
    int n = rem % N;
    int l = rem / N;
    float v = (k < K) ? src[((size_t)l * K + k) * N + n] : 0.f;
    dst[idx] = f2bf(v);
}

// ---------------- kernel regression feats: 16 blocks = (b,q) ----------------
__global__ __launch_bounds__(256) void feats_k(
    const float* __restrict__ gxy, const float* __restrict__ goff,
    const float* __restrict__ bws, const float* __restrict__ g0,
    const float* __restrict__ sloc, float* __restrict__ feats) {
    int b = blockIdx.x >> 1, q = blockIdx.x & 1;
    float qx = sloc[b * 4 + q * 2 + 0];
    float qy = sloc[b * 4 + q * 2 + 1];
    float swt = 0.f;
    float sf[64];
#pragma unroll
    for (int c = 0; c < 64; c++) sf[c] = 0.f;
    for (int i = threadIdx.x; i < NPTS; i += 256) {
        float gx = gxy[i * 2 + 0] + tanhf(goff[i * 2 + 0]) * 0.1f;
        float gy = gxy[i * 2 + 1] + tanhf(goff[i * 2 + 1]) * 0.1f;
        float bw = fminf(fmaxf(bws[i], 0.1f), 0.5f);
        float dx = qx - gx, dy = qy - gy;
        float w = expf(-(dx * dx + dy * dy) / (bw * bw));
        swt += w;
#pragma unroll
        for (int c = 0; c < 64; c++) sf[c] += w * g0[(size_t)i * 64 + c];
    }
#pragma unroll
    for (int c = 0; c < 64; c++)
        for (int o = 32; o; o >>= 1) sf[c] += __shfl_down(sf[c], o);
    for (int o = 32; o; o >>= 1) swt += __shfl_down(swt, o);
    __shared__ float red[4][65];
    int lane = threadIdx.x & 63, wv = threadIdx.x >> 6;
    if (lane == 0) {
#pragma unroll
        for (int c = 0; c < 64; c++) red[wv][c] = sf[c];
        red[wv][64] = swt;
    }
    __syncthreads();
    if (threadIdx.x < 64) {
        int c = threadIdx.x;
        float t = red[0][c] + red[1][c] + red[2][c] + red[3][c];
        float s = red[0][64] + red[1][64] + red[2][64] + red[3][64];
        feats[b * 128 + q * 64 + c] = t / s;
    }
}

// ---------------- build my_input bf16 [16000][256]: [feat0|feat1|input_stuff|pad0] ----------
__global__ void build_k(const float* __restrict__ feats, const float* __restrict__ inp,
                        unsigned short* __restrict__ dst) {
    int idx = blockIdx.x * 256 + threadIdx.x;   // 16000*256 threads
    int c = idx & 255;
    int m = idx >> 8;
    int b = m / SS;
    float v;
    if (c < 128) v = feats[b * 128 + c];
    else if (c < CATCH) v = inp[(size_t)m * IN_CH + (c - 128)];
    else v = 0.f;
    dst[idx] = f2bf(v);
}

// ---------------- MFMA GEMM: C[M,512] = A[M,K] @ W[K,512], tiles 128x128, BK=32 ----------
// A: bf16 [M][K] row-major. BT: bf16 [512][K] (W transposed). Both staged via
// global_load_lds with XOR swizzle slot^=(row^(row>>2))&3, read ds_read_b128.
// EPI: 0=PROJ(expand x4 +ch0, leaky, bf16) 1=LAYER 2=LAYER+RES 3=LAYER_LAST(no leaky)
//      4=SIMPLE+leaky 5=SIMPLE
template <int EPI>
__global__ __launch_bounds__(256) void gemm_k(
    const unsigned short* __restrict__ A, const unsigned short* __restrict__ BT,
    unsigned short* __restrict__ out, int K,
    const float* __restrict__ bias, const float* __restrict__ chan,
    const unsigned short* __restrict__ resid) {
    __shared__ unsigned short lds[2][4096];     // A tile 8KB, B tile 8KB
    const int tid = threadIdx.x;
    const int lane = tid & 63, wv = tid >> 6;
    const int wm = wv >> 1, wn = wv & 1;
    const int c8 = lane >> 4;                   // k-chunk 0..3
    const int fr = lane & 15;

    // fragment LDS offsets (ushort units), constant over K loop
    int aoff[4], boff[4];
#pragma unroll
    for (int i = 0; i < 4; i++) {
        int ra = wm * 64 + i * 16 + fr;
        aoff[i] = ra * 32 + ((c8 ^ ((ra ^ (ra >> 2)) & 3)) << 3);
        int rb = wn * 64 + i * 16 + fr;
        boff[i] = rb * 32 + ((c8 ^ ((rb ^ (rb >> 2)) & 3)) << 3);
    }
    // staging: LDS byte offset o = issue*4096 + wv*1024 + lane*16 (linear), source swizzled
    const int o1 = wv * 1024 + lane * 16;
    const int o2 = o1 + 4096;
    const int r1 = o1 >> 6, s1 = (o1 >> 4) & 3;
    const int r2 = o2 >> 6, s2 = (o2 >> 4) & 3;
    const int g1 = (s1 ^ ((r1 ^ (r1 >> 2)) & 3)) << 3;  // element offset within BK
    const int g2 = (s2 ^ ((r2 ^ (r2 >> 2)) & 3)) << 3;
    const unsigned short* Ab = A + (size_t)blockIdx.x * 128 * K;
    const unsigned short* Bb = BT + (size_t)blockIdx.y * 128 * K;
    const size_t a1 = (size_t)r1 * K + g1, a2 = (size_t)r2 * K + g2;

    f32x4 acc[4][4];
#pragma unroll
    for (int i = 0; i < 4; i++)
#pragma unroll
        for (int j = 0; j < 4; j++) acc[i][j] = (f32x4)0.f;

    const int nK = K >> 5;
    for (int kt = 0; kt < nK; ++kt) {
        const int k0 = kt << 5;
        __syncthreads();
        gload16(Ab + a1 + k0, &lds[0][o1 >> 1]);
        gload16(Ab + a2 + k0, &lds[0][o2 >> 1]);
        gload16(Bb + a1 + k0, &lds[1][o1 >> 1]);
        gload16(Bb + a2 + k0, &lds[1][o2 >> 1]);
        __syncthreads();
        bf16x8 av[4], bv[4];
#pragma unroll
        for (int i = 0; i < 4; i++) av[i] = *(const bf16x8*)&lds[0][aoff[i]];
#pragma unroll
        for (int i = 0; i < 4; i++) bv[i] = *(const bf16x8*)&lds[1][boff[i]];
#pragma unroll
        for (int i = 0; i < 4; i++)
#pragma unroll
            for (int j = 0; j < 4; j++)
                acc[i][j] = __builtin_amdgcn_mfma_f32_16x16x32_bf16(av[i], bv[j], acc[i][j], 0, 0, 0);
    }

    // epilogue: C/D frag: col = lane&15, row = (lane>>4)*4 + reg   [m89-verified]
    const int rbase = (lane >> 4) << 2;
    const size_t m0 = (size_t)blockIdx.x * 128;
    const int n0 = blockIdx.y * 128;
#pragma unroll
    for (int i = 0; i < 4; i++) {
#pragma unroll
        for (int j = 0; j < 4; j++) {
#pragma unroll
            for (int rg = 0; rg < 4; ++rg) {
                size_t m = m0 + wm * 64 + i * 16 + rbase + rg;
                int n = n0 + wn * 64 + j * 16 + fr;
                float v = acc[i][j][rg];
                if constexpr (EPI == 0) {
                    float v0 = v + bias[n];
#pragma unroll
                    for (int d = 0; d < 4; ++d) {
                        float u = v0 + chan[d * 512 + n];
                        out[(m * 4 + d) * 512 + n] = f2bf(leaky(u));
                    }
                } else if constexpr (EPI == 1 || EPI == 2 || EPI == 3) {
                    int d = (int)(m & 3);
                    float u = v + bias[n] + chan[d * 512 + n];
                    if constexpr (EPI == 2) u += bf2f(resid[(m >> 2) * 512 + n]);
                    out[m * 512 + n] = f2bf(EPI == 3 ? u : leaky(u));
                } else {
                    float u = v + bias[n];
                    out[m * 512 + n] = f2bf(EPI == 4 ? leaky(u) : u);
                }
            }
        }
    }
}

// ---------------- final: out[64000][2] = A @ out_W + out_b, one wave per row -------------
__global__ __launch_bounds__(256) void final_k(
    const unsigned short* __restrict__ A, const float* __restrict__ outW,
    const float* __restrict__ outb, float* __restrict__ out) {
    int gw = blockIdx.x * 4 + (threadIdx.x >> 6);
    int lane = threadIdx.x & 63;
    const unsigned short* row = A + (size_t)gw * 512;
    uint4 bits = *(const uint4*)(row + lane * 8);
    unsigned int ww[4] = {bits.x, bits.y, bits.z, bits.w};
    float s0 = 0.f, s1 = 0.f;
#pragma unroll
    for (int j = 0; j < 8; j++) {
        unsigned short u = (unsigned short)((ww[j >> 1] >> ((j & 1) * 16)) & 0xffff);
        float a = bf2f(u);
        int k = lane * 8 + j;
        s0 = fmaf(a, outW[k * 2 + 0], s0);
        s1 = fmaf(a, outW[k * 2 + 1], s1);
    }
    for (int o = 32; o; o >>= 1) {
        s0 += __shfl_down(s0, o);
        s1 += __shfl_down(s1, o);
    }
    if (lane == 0) {
        out[(size_t)gw * 2 + 0] = s0 + outb[0];
        out[(size_t)gw * 2 + 1] = s1 + outb[1];
    }
}

extern "C" void kernel_launch(void* const* d_in, const int* in_sizes, int n_in,
                              void* d_out, int out_size, void* d_ws, size_t ws_size,
                              hipStream_t stream) {
    const float* input_stuff = (const float*)d_in[0];
    const float* sound_loc   = (const float*)d_in[1];
    const float* grid_xy     = (const float*)d_in[2];
    const float* xy_offset   = (const float*)d_in[3];
    const float* bandwidths  = (const float*)d_in[4];
    const float* grid_0      = (const float*)d_in[5];
    const float* proj_W      = (const float*)d_in[6];
    const float* proj_b      = (const float*)d_in[7];
    const float* res_W0      = (const float*)d_in[8];
    const float* res_b0      = (const float*)d_in[9];
    const float* res_W1      = (const float*)d_in[10];
    const float* res_b1      = (const float*)d_in[11];
    const float* layers_W    = (const float*)d_in[12];
    const float* layers_b    = (const float*)d_in[13];
    const float* channels    = (const float*)d_in[14];
    const float* out_W       = (const float*)d_in[15];
    const float* out_b       = (const float*)d_in[16];

    char* ws = (char*)d_ws;
    float* feats            = (float*)(ws + OFF_FEATS);
    unsigned short* projWT  = (unsigned short*)(ws + OFF_PROJWT);
    unsigned short* res0WT  = (unsigned short*)(ws + OFF_RES0WT);
    unsigned short* res1WT  = (unsigned short*)(ws + OFF_RES1WT);
    unsigned short* layWT   = (unsigned short*)(ws + OFF_LAYWT);
    unsigned short* myin    = (unsigned short*)(ws + OFF_MYIN);
    unsigned short* R0      = (unsigned short*)(ws + OFF_R0);
    unsigned short* Rb      = (unsigned short*)(ws + OFF_R);
    unsigned short* A0      = (unsigned short*)(ws + OFF_A0);
    unsigned short* A1      = (unsigned short*)(ws + OFF_A1);

    // weights -> transposed/padded bf16
    wconv_k<<<(512 * 256 + 255) / 256, 256, 0, stream>>>(proj_W, projWT, CATCH, CATPAD, IC, 512 * 256);
    wconv_k<<<(512 * 256 + 255) / 256, 256, 0, stream>>>(res_W0, res0WT, CATCH, CATPAD, IC, 512 * 256);
    wconv_k<<<(512 * 512 + 255) / 256, 256, 0, stream>>>(res_W1, res1WT, IC, IC, IC, 512 * 512);
    wconv_k<<<(6 * 512 * 512 + 255) / 256, 256, 0, stream>>>(layers_W, layWT, IC, IC, IC, 6 * 512 * 512);

    feats_k<<<16, 256, 0, stream>>>(grid_xy, xy_offset, bandwidths, grid_0, sound_loc, feats);
    build_k<<<MROWS, 256, 0, stream>>>(feats, input_stuff, myin);

    dim3 g16(125, 4), g64(500, 4);
    // proj (+channels[0], leaky, expand x4) -> A0
    gemm_k<0><<<g16, 256, 0, stream>>>(myin, projWT, A0, CATPAD, proj_b, channels, nullptr);
    // residual branch
    gemm_k<4><<<g16, 256, 0, stream>>>(myin, res0WT, R0, CATPAD, res_b0, nullptr, nullptr);
    gemm_k<5><<<g16, 256, 0, stream>>>(R0, res1WT, Rb, IC, res_b1, nullptr, nullptr);
    // 6 layers, ping-pong A0/A1; residual added at k==2; k==5 last (no leaky)
    gemm_k<1><<<g64, 256, 0, stream>>>(A0, layWT + 0 * 262144, A1, IC, layers_b + 0 * 512, channels + 1 * 2048, nullptr);
    gemm_k<1><<<g64, 256, 0, stream>>>(A1, layWT + 1 * 262144, A0, IC, layers_b + 1 * 512, channels + 2 * 2048, nullptr);
    gemm_k<2><<<g64, 256, 0, stream>>>(A0, layWT + 2 * 262144, A1, IC, layers_b + 2 * 512, channels + 3 * 2048, Rb);
    gemm_k<1><<<g64, 256, 0, stream>>>(A1, layWT + 3 * 262144, A0, IC, layers_b + 3 * 512, channels + 4 * 2048, nullptr);
    gemm_k<1><<<g64, 256, 0, stream>>>(A0, layWT + 4 * 262144, A1, IC, layers_b + 4 * 512, channels + 5 * 2048, nullptr);
    gemm_k<3><<<g64, 256, 0, stream>>>(A1, layWT + 5 * 262144, A0, IC, layers_b + 5 * 512, channels + 6 * 2048, nullptr);

    final_k<<<MROWS, 256, 0, stream>>>(A0, out_W, out_b, (float*)d_out);
}

// Round 2
// 501.265 us; speedup vs baseline: 1.2358x; 1.2358x over previous
//
#include <hip/hip_runtime.h>
#include <hip/hip_bf16.h>

// ---------------- problem constants ----------------
#define BB 8
#define SS 2000
#define IN_CH 120
#define GRID_CH 64
#define NPTS 10000
#define IC 512
#define DIRS 4
#define CATCH 248
#define CATPAD 256
#define NLAY 6
#define MROWS 16000          // B*S
#define MROWS4 64000         // B*S*DIRS
#define NSLICE 16
#define PTS_PER_SLICE 625    // 10000/16

typedef __bf16 bf16x8 __attribute__((ext_vector_type(8)));
typedef float f32x4 __attribute__((ext_vector_type(4)));

#define DEVI __device__ __forceinline__

DEVI unsigned short f2bf(float f) {
    __hip_bfloat16 h = __float2bfloat16(f);
    return __builtin_bit_cast(unsigned short, h);
}
DEVI float bf2f(unsigned short u) {
    unsigned int x = ((unsigned int)u) << 16;
    return __builtin_bit_cast(float, x);
}
DEVI float leaky(float x) { return x > 0.f ? x : 0.1f * x; }

DEVI void gload16(const void* g, void* l) {
    __builtin_amdgcn_global_load_lds(
        (const unsigned int __attribute__((address_space(1)))*)g,
        (unsigned int __attribute__((address_space(3)))*)l, 16, 0, 0);
}

// ---------------- workspace layout (bytes) ----------------
static const size_t OFF_FEATS  = 0;            // 8*128 f32            = 4096
static const size_t OFF_PROJWT = 4096;         // 512*256 bf16         = 262144
static const size_t OFF_RES0WT = 266240;       // 512*256 bf16
static const size_t OFF_RES1WT = 528384;       // 512*512 bf16         = 524288
static const size_t OFF_LAYWT  = 1052672;      // 6*512*512 bf16       = 3145728
static const size_t OFF_MYIN   = 4198400;      // 16000*256 bf16       = 8192000
static const size_t OFF_R0     = 12390400;     // 16000*512 bf16       = 16384000
static const size_t OFF_R      = 28774400;     // 16000*512 bf16
static const size_t OFF_A0     = 45158400;     // 64000*512 bf16       = 65536000
static const size_t OFF_A1     = 110694400;    // 64000*512 bf16  (end 176230400)
// feats partials overlap A0 (consumed by feats_reduce BEFORE proj GEMM writes A0)

// ---------------- weight convert: f32 [L][K][N] -> bf16 [L][N][Kpad] (transposed, pad K) ----
__global__ void wconv_k(const float* __restrict__ src, unsigned short* __restrict__ dst,
                        int K, int Kpad, int N, int total) {
    int idx = blockIdx.x * 256 + threadIdx.x;
    if (idx >= total) return;
    int k = idx % Kpad;
    int rem = idx / Kpad;
    int n = rem % N;
    int l = rem / N;
    float v = (k < K) ? src[((size_t)l * K + k) * N + n] : 0.f;
    dst[idx] = f2bf(v);
}

// ---------------- kernel regression, stage 1: partial sums over point slices ----------------
// grid (16 bq, NSLICE), 256 threads. partial[(slice*16+bq)*72 + c], c<64 = num, c==64 = den
__global__ __launch_bounds__(256) void feats_part_k(
    const float* __restrict__ gxy, const float* __restrict__ goff,
    const float* __restrict__ bws, const float* __restrict__ g0,
    const float* __restrict__ sloc, float* __restrict__ partial) {
    int bq = blockIdx.x;
    int b = bq >> 1, q = bq & 1;
    float qx = sloc[b * 4 + q * 2 + 0];
    float qy = sloc[b * 4 + q * 2 + 1];
    int i0 = blockIdx.y * PTS_PER_SLICE;
    int iend = i0 + PTS_PER_SLICE;
    float swt = 0.f;
    float sf[64];
#pragma unroll
    for (int c = 0; c < 64; c++) sf[c] = 0.f;
    for (int i = i0 + threadIdx.x; i < iend; i += 256) {
        float gx = gxy[i * 2 + 0] + tanhf(goff[i * 2 + 0]) * 0.1f;
        float gy = gxy[i * 2 + 1] + tanhf(goff[i * 2 + 1]) * 0.1f;
        float bw = fminf(fmaxf(bws[i], 0.1f), 0.5f);
        float dx = qx - gx, dy = qy - gy;
        float w = expf(-(dx * dx + dy * dy) / (bw * bw));
        swt += w;
#pragma unroll
        for (int c = 0; c < 64; c++) sf[c] += w * g0[(size_t)i * 64 + c];
    }
#pragma unroll
    for (int c = 0; c < 64; c++)
        for (int o = 32; o; o >>= 1) sf[c] += __shfl_down(sf[c], o);
    for (int o = 32; o; o >>= 1) swt += __shfl_down(swt, o);
    __shared__ float red[4][65];
    int lane = threadIdx.x & 63, wv = threadIdx.x >> 6;
    if (lane == 0) {
#pragma unroll
        for (int c = 0; c < 64; c++) red[wv][c] = sf[c];
        red[wv][64] = swt;
    }
    __syncthreads();
    size_t base = (size_t)(blockIdx.y * 16 + bq) * 72;
    if (threadIdx.x < 64) {
        int c = threadIdx.x;
        partial[base + c] = red[0][c] + red[1][c] + red[2][c] + red[3][c];
        if (c == 0)
            partial[base + 64] = red[0][64] + red[1][64] + red[2][64] + red[3][64];
    }
}

// ---------------- stage 2: sum slices, divide ----------------
__global__ __launch_bounds__(128) void feats_reduce_k(
    const float* __restrict__ partial, float* __restrict__ feats) {
    int bq = blockIdx.x;
    __shared__ float s[66];
    int t = threadIdx.x;
    if (t < 65) {
        float acc = 0.f;
        for (int sl = 0; sl < NSLICE; ++sl)
            acc += partial[(size_t)(sl * 16 + bq) * 72 + t];
        s[t] = acc;
    }
    __syncthreads();
    if (t < 64) {
        int b = bq >> 1, q = bq & 1;
        feats[b * 128 + q * 64 + t] = s[t] / s[64];
    }
}

// ---------------- build my_input bf16 [16000][256]: [feat0|feat1|input_stuff|pad0] ----------
__global__ void build_k(const float* __restrict__ feats, const float* __restrict__ inp,
                        unsigned short* __restrict__ dst) {
    int idx = blockIdx.x * 256 + threadIdx.x;   // 16000*256 threads
    int c = idx & 255;
    int m = idx >> 8;
    int b = m / SS;
    float v;
    if (c < 128) v = feats[b * 128 + c];
    else if (c < CATCH) v = inp[(size_t)m * IN_CH + (c - 128)];
    else v = 0.f;
    dst[idx] = f2bf(v);
}

// ---------------- MFMA GEMM: C[M,512] = A[M,K] @ W[K,512], tiles 128x128, BK=64 ----------
// A: bf16 [M][K] row-major. BT: bf16 [512][K] (W transposed). Staged via global_load_lds
// (linear LDS dest, pre-swizzled global source); swizzle: 16B-chunk p = c ^ (row&7).
// EPI: 0=PROJ(expand x4 +ch0, leaky) 1=LAYER 2=LAYER+RES 3=LAYER_LAST(no leaky)
//      4=SIMPLE+leaky 5=SIMPLE
template <int EPI>
__global__ __launch_bounds__(256) void gemm_k(
    const unsigned short* __restrict__ A, const unsigned short* __restrict__ BT,
    unsigned short* __restrict__ out, int K,
    const float* __restrict__ bias, const float* __restrict__ chan,
    const unsigned short* __restrict__ resid) {
    __shared__ unsigned short ldsA[8192];      // 128 rows x 64 k
    __shared__ unsigned short ldsB[8192];
    const int tid = threadIdx.x;
    const int lane = tid & 63, wv = tid >> 6;
    const int wm = wv >> 1, wn = wv & 1;
    const int c8 = lane >> 4;                   // k-chunk within half 0..3
    const int fr = lane & 15;

    // fragment LDS offsets (ushort units): [frag][half]
    int aoff[4][2], boff[4][2];
#pragma unroll
    for (int i = 0; i < 4; i++) {
        int ra = wm * 64 + i * 16 + fr;
        int rb = wn * 64 + i * 16 + fr;
#pragma unroll
        for (int h = 0; h < 2; h++) {
            int c = c8 + h * 4;
            aoff[i][h] = ra * 64 + ((c ^ (ra & 7)) << 3);
            boff[i][h] = rb * 64 + ((c ^ (rb & 7)) << 3);
        }
    }
    // staging: 4 issues of 16B per thread per tile; LDS linear, source pre-swizzled
    int ldso[4];
    size_t asrc[4];
    const unsigned short* Ab = A + (size_t)blockIdx.x * 128 * K;
    const unsigned short* Bb = BT + (size_t)blockIdx.y * 128 * K;
#pragma unroll
    for (int t = 0; t < 4; t++) {
        int o = t * 4096 + wv * 1024 + lane * 16;   // bytes
        int r = o >> 7;
        int s = (o >> 4) & 7;
        int g = (s ^ (r & 7)) << 3;                 // element offset within BK window
        ldso[t] = o >> 1;                           // ushort units
        asrc[t] = (size_t)r * K + g;
    }

    f32x4 acc[4][4];
#pragma unroll
    for (int i = 0; i < 4; i++)
#pragma unroll
        for (int j = 0; j < 4; j++) acc[i][j] = (f32x4)0.f;

    const int nK = K >> 6;
    for (int kt = 0; kt < nK; ++kt) {
        const int k0 = kt << 6;
        __syncthreads();
#pragma unroll
        for (int t = 0; t < 4; t++) gload16(Ab + asrc[t] + k0, &ldsA[ldso[t]]);
#pragma unroll
        for (int t = 0; t < 4; t++) gload16(Bb + asrc[t] + k0, &ldsB[ldso[t]]);
        __syncthreads();
#pragma unroll
        for (int h = 0; h < 2; h++) {
            bf16x8 av[4], bv[4];
#pragma unroll
            for (int i = 0; i < 4; i++) av[i] = *(const bf16x8*)&ldsA[aoff[i][h]];
#pragma unroll
            for (int j = 0; j < 4; j++) bv[j] = *(const bf16x8*)&ldsB[boff[j][h]];
#pragma unroll
            for (int i = 0; i < 4; i++)
#pragma unroll
                for (int j = 0; j < 4; j++)
                    acc[i][j] = __builtin_amdgcn_mfma_f32_16x16x32_bf16(av[i], bv[j], acc[i][j], 0, 0, 0);
        }
    }

    // epilogue: C/D frag: col = lane&15, row = (lane>>4)*4 + reg   [m89-verified]
    const int rbase = (lane >> 4) << 2;
    const size_t m0 = (size_t)blockIdx.x * 128;
    const int n0 = blockIdx.y * 128;
#pragma unroll
    for (int i = 0; i < 4; i++) {
#pragma unroll
        for (int j = 0; j < 4; j++) {
#pragma unroll
            for (int rg = 0; rg < 4; ++rg) {
                size_t m = m0 + wm * 64 + i * 16 + rbase + rg;
                int n = n0 + wn * 64 + j * 16 + fr;
                float v = acc[i][j][rg];
                if constexpr (EPI == 0) {
                    float v0 = v + bias[n];
#pragma unroll
                    for (int d = 0; d < 4; ++d) {
                        float u = v0 + chan[d * 512 + n];
                        out[(m * 4 + d) * 512 + n] = f2bf(leaky(u));
                    }
                } else if constexpr (EPI == 1 || EPI == 2 || EPI == 3) {
                    int d = (int)(m & 3);
                    float u = v + bias[n] + chan[d * 512 + n];
                    if constexpr (EPI == 2) u += bf2f(resid[(m >> 2) * 512 + n]);
                    out[m * 512 + n] = f2bf(EPI == 3 ? u : leaky(u));
                } else {
                    float u = v + bias[n];
                    out[m * 512 + n] = f2bf(EPI == 4 ? leaky(u) : u);
                }
            }
        }
    }
}

// ---------------- final: out[64000][2] = A @ out_W + out_b, one wave per row -------------
__global__ __launch_bounds__(256) void final_k(
    const unsigned short* __restrict__ A, const float* __restrict__ outW,
    const float* __restrict__ outb, float* __restrict__ out) {
    int gw = blockIdx.x * 4 + (threadIdx.x >> 6);
    int lane = threadIdx.x & 63;
    const unsigned short* row = A + (size_t)gw * 512;
    uint4 bits = *(const uint4*)(row + lane * 8);
    unsigned int ww[4] = {bits.x, bits.y, bits.z, bits.w};
    float s0 = 0.f, s1 = 0.f;
#pragma unroll
    for (int j = 0; j < 8; j++) {
        unsigned short u = (unsigned short)((ww[j >> 1] >> ((j & 1) * 16)) & 0xffff);
        float a = bf2f(u);
        int k = lane * 8 + j;
        s0 = fmaf(a, outW[k * 2 + 0], s0);
        s1 = fmaf(a, outW[k * 2 + 1], s1);
    }
    for (int o = 32; o; o >>= 1) {
        s0 += __shfl_down(s0, o);
        s1 += __shfl_down(s1, o);
    }
    if (lane == 0) {
        out[(size_t)gw * 2 + 0] = s0 + outb[0];
        out[(size_t)gw * 2 + 1] = s1 + outb[1];
    }
}

extern "C" void kernel_launch(void* const* d_in, const int* in_sizes, int n_in,
                              void* d_out, int out_size, void* d_ws, size_t ws_size,
                              hipStream_t stream) {
    const float* input_stuff = (const float*)d_in[0];
    const float* sound_loc   = (const float*)d_in[1];
    const float* grid_xy     = (const float*)d_in[2];
    const float* xy_offset   = (const float*)d_in[3];
    const float* bandwidths  = (const float*)d_in[4];
    const float* grid_0      = (const float*)d_in[5];
    const float* proj_W      = (const float*)d_in[6];
    const float* proj_b      = (const float*)d_in[7];
    const float* res_W0      = (const float*)d_in[8];
    const float* res_b0      = (const float*)d_in[9];
    const float* res_W1      = (const float*)d_in[10];
    const float* res_b1      = (const float*)d_in[11];
    const float* layers_W    = (const float*)d_in[12];
    const float* layers_b    = (const float*)d_in[13];
    const float* channels    = (const float*)d_in[14];
    const float* out_W       = (const float*)d_in[15];
    const float* out_b       = (const float*)d_in[16];

    char* ws = (char*)d_ws;
    float* feats            = (float*)(ws + OFF_FEATS);
    unsigned short* projWT  = (unsigned short*)(ws + OFF_PROJWT);
    unsigned short* res0WT  = (unsigned short*)(ws + OFF_RES0WT);
    unsigned short* res1WT  = (unsigned short*)(ws + OFF_RES1WT);
    unsigned short* layWT   = (unsigned short*)(ws + OFF_LAYWT);
    unsigned short* myin    = (unsigned short*)(ws + OFF_MYIN);
    unsigned short* R0      = (unsigned short*)(ws + OFF_R0);
    unsigned short* Rb      = (unsigned short*)(ws + OFF_R);
    unsigned short* A0      = (unsigned short*)(ws + OFF_A0);
    unsigned short* A1      = (unsigned short*)(ws + OFF_A1);
    float* partial          = (float*)(ws + OFF_A0);   // reused before A0 is written

    // weights -> transposed/padded bf16
    wconv_k<<<(512 * 256 + 255) / 256, 256, 0, stream>>>(proj_W, projWT, CATCH, CATPAD, IC, 512 * 256);
    wconv_k<<<(512 * 256 + 255) / 256, 256, 0, stream>>>(res_W0, res0WT, CATCH, CATPAD, IC, 512 * 256);
    wconv_k<<<(512 * 512 + 255) / 256, 256, 0, stream>>>(res_W1, res1WT, IC, IC, IC, 512 * 512);
    wconv_k<<<(6 * 512 * 512 + 255) / 256, 256, 0, stream>>>(layers_W, layWT, IC, IC, IC, 6 * 512 * 512);

    feats_part_k<<<dim3(16, NSLICE), 256, 0, stream>>>(grid_xy, xy_offset, bandwidths, grid_0, sound_loc, partial);
    feats_reduce_k<<<16, 128, 0, stream>>>(partial, feats);
    build_k<<<MROWS, 256, 0, stream>>>(feats, input_stuff, myin);

    dim3 g16(125, 4), g64(500, 4);
    // proj (+channels[0], leaky, expand x4) -> A0
    gemm_k<0><<<g16, 256, 0, stream>>>(myin, projWT, A0, CATPAD, proj_b, channels, nullptr);
    // residual branch
    gemm_k<4><<<g16, 256, 0, stream>>>(myin, res0WT, R0, CATPAD, res_b0, nullptr, nullptr);
    gemm_k<5><<<g16, 256, 0, stream>>>(R0, res1WT, Rb, IC, res_b1, nullptr, nullptr);
    // 6 layers, ping-pong A0/A1; residual added at k==2; k==5 last (no leaky)
    gemm_k<1><<<g64, 256, 0, stream>>>(A0, layWT + 0 * 262144, A1, IC, layers_b + 0 * 512, channels + 1 * 2048, nullptr);
    gemm_k<1><<<g64, 256, 0, stream>>>(A1, layWT + 1 * 262144, A0, IC, layers_b + 1 * 512, channels + 2 * 2048, nullptr);
    gemm_k<2><<<g64, 256, 0, stream>>>(A0, layWT + 2 * 262144, A1, IC, layers_b + 2 * 512, channels + 3 * 2048, Rb);
    gemm_k<1><<<g64, 256, 0, stream>>>(A1, layWT + 3 * 262144, A0, IC, layers_b + 3 * 512, channels + 4 * 2048, nullptr);
    gemm_k<1><<<g64, 256, 0, stream>>>(A0, layWT + 4 * 262144, A1, IC, layers_b + 4 * 512, channels + 5 * 2048, nullptr);
    gemm_k<3><<<g64, 256, 0, stream>>>(A1, layWT + 5 * 262144, A0, IC, layers_b + 5 * 512, channels + 6 * 2048, nullptr);

    final_k<<<MROWS, 256, 0, stream>>>(A0, out_W, out_b, (float*)d_out);
}

// Round 3
// 403.815 us; speedup vs baseline: 1.5340x; 1.2413x over previous
//
#include <hip/hip_runtime.h>
#include <hip/hip_bf16.h>

// ---------------- problem constants ----------------
#define BB 8
#define SS 2000
#define IN_CH 120
#define GRID_CH 64
#define NPTS 10000
#define IC 512
#define DIRS 4
#define CATCH 248
#define CATPAD 256
#define NLAY 6
#define MROWS 16000          // B*S
#define MROWS4 64000         // B*S*DIRS
#define NSLICE 16
#define PTS_PER_SLICE 625    // 10000/16

typedef __bf16 bf16x8 __attribute__((ext_vector_type(8)));
typedef float f32x4 __attribute__((ext_vector_type(4)));

#define DEVI __device__ __forceinline__

DEVI unsigned short f2bf(float f) {
    __hip_bfloat16 h = __float2bfloat16(f);
    return __builtin_bit_cast(unsigned short, h);
}
DEVI float bf2f(unsigned short u) {
    unsigned int x = ((unsigned int)u) << 16;
    return __builtin_bit_cast(float, x);
}
DEVI float leaky(float x) { return x > 0.f ? x : 0.1f * x; }

DEVI void gload16(const void* g, void* l) {
    __builtin_amdgcn_global_load_lds(
        (const unsigned int __attribute__((address_space(1)))*)g,
        (unsigned int __attribute__((address_space(3)))*)l, 16, 0, 0);
}

// XCD-chunked bijective swizzle (m204): same-panel blocks land consecutively
// within one XCD's contiguous chunk -> A-panel L2 reuse.
DEVI int xcd_swizzle() {
    int nwg = (int)gridDim.x;
    int orig = (int)blockIdx.x;
    int q = nwg >> 3, r = nwg & 7;
    int xcd = orig & 7, pos = orig >> 3;
    int base = xcd < r ? xcd * (q + 1) : r * (q + 1) + (xcd - r) * q;
    return base + pos;
}

// ---------------- workspace layout (bytes) ----------------
static const size_t OFF_FEATS  = 0;            // 8*128 f32            = 4096
static const size_t OFF_PROJWT = 4096;         // 512*256 bf16         = 262144
static const size_t OFF_RES0WT = 266240;       // 512*256 bf16
static const size_t OFF_RES1WT = 528384;       // 512*512 bf16         = 524288
static const size_t OFF_LAYWT  = 1052672;      // 6*512*512 bf16       = 3145728
static const size_t OFF_MYIN   = 4198400;      // 16000*256 bf16       = 8192000
static const size_t OFF_R0     = 12390400;     // 16000*512 bf16       = 16384000
static const size_t OFF_R      = 28774400;     // 16000*512 bf16
static const size_t OFF_A0     = 45158400;     // 64000*512 bf16       = 65536000
static const size_t OFF_A1     = 110694400;    // 64000*512 bf16  (end 176230400)
// feats partials overlap A0 (consumed by feats_reduce BEFORE proj GEMM writes A0)

// ---------------- weight convert: f32 [L][K][N] -> bf16 [L][N][Kpad] (transposed, pad K) ----
__global__ void wconv_k(const float* __restrict__ src, unsigned short* __restrict__ dst,
                        int K, int Kpad, int N, int total) {
    int idx = blockIdx.x * 256 + threadIdx.x;
    if (idx >= total) return;
    int k = idx % Kpad;
    int rem = idx / Kpad;
    int n = rem % N;
    int l = rem / N;
    float v = (k < K) ? src[((size_t)l * K + k) * N + n] : 0.f;
    dst[idx] = f2bf(v);
}

// ---------------- kernel regression, stage 1: partial sums over point slices ----------------
__global__ __launch_bounds__(256) void feats_part_k(
    const float* __restrict__ gxy, const float* __restrict__ goff,
    const float* __restrict__ bws, const float* __restrict__ g0,
    const float* __restrict__ sloc, float* __restrict__ partial) {
    int bq = blockIdx.x;
    int b = bq >> 1, q = bq & 1;
    float qx = sloc[b * 4 + q * 2 + 0];
    float qy = sloc[b * 4 + q * 2 + 1];
    int i0 = blockIdx.y * PTS_PER_SLICE;
    int iend = i0 + PTS_PER_SLICE;
    float swt = 0.f;
    float sf[64];
#pragma unroll
    for (int c = 0; c < 64; c++) sf[c] = 0.f;
    for (int i = i0 + threadIdx.x; i < iend; i += 256) {
        float gx = gxy[i * 2 + 0] + tanhf(goff[i * 2 + 0]) * 0.1f;
        float gy = gxy[i * 2 + 1] + tanhf(goff[i * 2 + 1]) * 0.1f;
        float bw = fminf(fmaxf(bws[i], 0.1f), 0.5f);
        float dx = qx - gx, dy = qy - gy;
        float w = expf(-(dx * dx + dy * dy) / (bw * bw));
        swt += w;
#pragma unroll
        for (int c = 0; c < 64; c++) sf[c] += w * g0[(size_t)i * 64 + c];
    }
#pragma unroll
    for (int c = 0; c < 64; c++)
        for (int o = 32; o; o >>= 1) sf[c] += __shfl_down(sf[c], o);
    for (int o = 32; o; o >>= 1) swt += __shfl_down(swt, o);
    __shared__ float red[4][65];
    int lane = threadIdx.x & 63, wv = threadIdx.x >> 6;
    if (lane == 0) {
#pragma unroll
        for (int c = 0; c < 64; c++) red[wv][c] = sf[c];
        red[wv][64] = swt;
    }
    __syncthreads();
    size_t base = (size_t)(blockIdx.y * 16 + bq) * 72;
    if (threadIdx.x < 64) {
        int c = threadIdx.x;
        partial[base + c] = red[0][c] + red[1][c] + red[2][c] + red[3][c];
        if (c == 0)
            partial[base + 64] = red[0][64] + red[1][64] + red[2][64] + red[3][64];
    }
}

// ---------------- stage 2: sum slices, divide ----------------
__global__ __launch_bounds__(128) void feats_reduce_k(
    const float* __restrict__ partial, float* __restrict__ feats) {
    int bq = blockIdx.x;
    __shared__ float s[66];
    int t = threadIdx.x;
    if (t < 65) {
        float acc = 0.f;
        for (int sl = 0; sl < NSLICE; ++sl)
            acc += partial[(size_t)(sl * 16 + bq) * 72 + t];
        s[t] = acc;
    }
    __syncthreads();
    if (t < 64) {
        int b = bq >> 1, q = bq & 1;
        feats[b * 128 + q * 64 + t] = s[t] / s[64];
    }
}

// ---------------- build my_input bf16 [16000][256]: [feat0|feat1|input_stuff|pad0] ----------
__global__ void build_k(const float* __restrict__ feats, const float* __restrict__ inp,
                        unsigned short* __restrict__ dst) {
    int idx = blockIdx.x * 256 + threadIdx.x;   // 16000*256 threads
    int c = idx & 255;
    int m = idx >> 8;
    int b = m / SS;
    float v;
    if (c < 128) v = feats[b * 128 + c];
    else if (c < CATCH) v = inp[(size_t)m * IN_CH + (c - 128)];
    else v = 0.f;
    dst[idx] = f2bf(v);
}

// ---------------- MFMA GEMM: C[M,512] = A[M,K] @ W[K,512], tiles 128x128, BK=64 ----------
// 2-phase double-buffered (T3-minimum): stage tile t+1 before computing tile t;
// one counted-vmcnt(0)+raw-barrier per K-step (prefetch flies under compute).
// 1D grid, XCD-chunked swizzle, by = swz&3 (N), bx = swz>>2 (M panel).
// EPI: 0=PROJ(expand x4 +ch0, leaky) 1=LAYER 2=LAYER+RES 3=LAYER_LAST(no leaky)
//      4=SIMPLE+leaky 5=SIMPLE
template <int EPI>
__global__ __launch_bounds__(256) void gemm_k(
    const unsigned short* __restrict__ A, const unsigned short* __restrict__ BT,
    unsigned short* __restrict__ out, int K,
    const float* __restrict__ bias, const float* __restrict__ chan,
    const unsigned short* __restrict__ resid) {
    __shared__ __align__(16) unsigned short lds[2][2][8192];   // [buf][A/B][128x64]
    const int tid = threadIdx.x;
    const int lane = tid & 63, wv = tid >> 6;
    const int wm = wv >> 1, wn = wv & 1;
    const int c8 = lane >> 4;                   // k-chunk within half 0..3
    const int fr = lane & 15;

    const int swz = xcd_swizzle();
    const int bx = swz >> 2, by = swz & 3;

    // fragment LDS offsets (ushort units): [frag][half]
    int aoff[4][2], boff[4][2];
#pragma unroll
    for (int i = 0; i < 4; i++) {
        int ra = wm * 64 + i * 16 + fr;
        int rb = wn * 64 + i * 16 + fr;
#pragma unroll
        for (int h = 0; h < 2; h++) {
            int c = c8 + h * 4;
            aoff[i][h] = ra * 64 + ((c ^ (ra & 7)) << 3);
            boff[i][h] = rb * 64 + ((c ^ (rb & 7)) << 3);
        }
    }
    // staging: 4 issues of 16B per thread per tile; LDS linear, source pre-swizzled
    int ldso[4];
    size_t asrc[4];
    const unsigned short* Ab = A + (size_t)bx * 128 * K;
    const unsigned short* Bb = BT + (size_t)by * 128 * K;
#pragma unroll
    for (int t = 0; t < 4; t++) {
        int o = t * 4096 + wv * 1024 + lane * 16;   // bytes
        int r = o >> 7;
        int s = (o >> 4) & 7;
        int g = (s ^ (r & 7)) << 3;                 // element offset within BK window
        ldso[t] = o >> 1;                           // ushort units
        asrc[t] = (size_t)r * K + g;
    }

    f32x4 acc[4][4];
#pragma unroll
    for (int i = 0; i < 4; i++)
#pragma unroll
        for (int j = 0; j < 4; j++) acc[i][j] = (f32x4)0.f;

    const int nK = K >> 6;
    // prologue: stage tile 0 into buf 0
#pragma unroll
    for (int t = 0; t < 4; t++) gload16(Ab + asrc[t], &lds[0][0][ldso[t]]);
#pragma unroll
    for (int t = 0; t < 4; t++) gload16(Bb + asrc[t], &lds[0][1][ldso[t]]);
    asm volatile("s_waitcnt vmcnt(0)" ::: "memory");
    __builtin_amdgcn_s_barrier();
    __builtin_amdgcn_sched_barrier(0);

    int buf = 0;
    for (int kt = 0; kt < nK; ++kt) {
        if (kt + 1 < nK) {
            const int k1 = (kt + 1) << 6;
#pragma unroll
            for (int t = 0; t < 4; t++) gload16(Ab + asrc[t] + k1, &lds[buf ^ 1][0][ldso[t]]);
#pragma unroll
            for (int t = 0; t < 4; t++) gload16(Bb + asrc[t] + k1, &lds[buf ^ 1][1][ldso[t]]);
        }
#pragma unroll
        for (int h = 0; h < 2; h++) {
            bf16x8 av[4], bv[4];
#pragma unroll
            for (int i = 0; i < 4; i++) av[i] = *(const bf16x8*)&lds[buf][0][aoff[i][h]];
#pragma unroll
            for (int j = 0; j < 4; j++) bv[j] = *(const bf16x8*)&lds[buf][1][boff[j][h]];
#pragma unroll
            for (int i = 0; i < 4; i++)
#pragma unroll
                for (int j = 0; j < 4; j++)
                    acc[i][j] = __builtin_amdgcn_mfma_f32_16x16x32_bf16(av[i], bv[j], acc[i][j], 0, 0, 0);
        }
        if (kt + 1 < nK) {
            asm volatile("s_waitcnt vmcnt(0)" ::: "memory");
            __builtin_amdgcn_s_barrier();
            __builtin_amdgcn_sched_barrier(0);
        }
        buf ^= 1;
    }

    // epilogue: C/D frag: col = lane&15, row = (lane>>4)*4 + reg   [m89-verified]
    const int rbase = (lane >> 4) << 2;
    const size_t m0 = (size_t)bx * 128;
    const int n0 = by * 128;
#pragma unroll
    for (int i = 0; i < 4; i++) {
#pragma unroll
        for (int j = 0; j < 4; j++) {
#pragma unroll
            for (int rg = 0; rg < 4; ++rg) {
                size_t m = m0 + wm * 64 + i * 16 + rbase + rg;
                int n = n0 + wn * 64 + j * 16 + fr;
                float v = acc[i][j][rg];
                if constexpr (EPI == 0) {
                    float v0 = v + bias[n];
#pragma unroll
                    for (int d = 0; d < 4; ++d) {
                        float u = v0 + chan[d * 512 + n];
                        out[(m * 4 + d) * 512 + n] = f2bf(leaky(u));
                    }
                } else if constexpr (EPI == 1 || EPI == 2 || EPI == 3) {
                    int d = (int)(m & 3);
                    float u = v + bias[n] + chan[d * 512 + n];
                    if constexpr (EPI == 2) u += bf2f(resid[(m >> 2) * 512 + n]);
                    out[m * 512 + n] = f2bf(EPI == 3 ? u : leaky(u));
                } else {
                    float u = v + bias[n];
                    out[m * 512 + n] = f2bf(EPI == 4 ? leaky(u) : u);
                }
            }
        }
    }
}

// ---------------- final: out[64000][2] = A @ out_W + out_b, one wave per row -------------
__global__ __launch_bounds__(256) void final_k(
    const unsigned short* __restrict__ A, const float* __restrict__ outW,
    const float* __restrict__ outb, float* __restrict__ out) {
    int gw = blockIdx.x * 4 + (threadIdx.x >> 6);
    int lane = threadIdx.x & 63;
    const unsigned short* row = A + (size_t)gw * 512;
    uint4 bits = *(const uint4*)(row + lane * 8);
    unsigned int ww[4] = {bits.x, bits.y, bits.z, bits.w};
    float s0 = 0.f, s1 = 0.f;
#pragma unroll
    for (int j = 0; j < 8; j++) {
        unsigned short u = (unsigned short)((ww[j >> 1] >> ((j & 1) * 16)) & 0xffff);
        float a = bf2f(u);
        int k = lane * 8 + j;
        s0 = fmaf(a, outW[k * 2 + 0], s0);
        s1 = fmaf(a, outW[k * 2 + 1], s1);
    }
    for (int o = 32; o; o >>= 1) {
        s0 += __shfl_down(s0, o);
        s1 += __shfl_down(s1, o);
    }
    if (lane == 0) {
        out[(size_t)gw * 2 + 0] = s0 + outb[0];
        out[(size_t)gw * 2 + 1] = s1 + outb[1];
    }
}

extern "C" void kernel_launch(void* const* d_in, const int* in_sizes, int n_in,
                              void* d_out, int out_size, void* d_ws, size_t ws_size,
                              hipStream_t stream) {
    const float* input_stuff = (const float*)d_in[0];
    const float* sound_loc   = (const float*)d_in[1];
    const float* grid_xy     = (const float*)d_in[2];
    const float* xy_offset   = (const float*)d_in[3];
    const float* bandwidths  = (const float*)d_in[4];
    const float* grid_0      = (const float*)d_in[5];
    const float* proj_W      = (const float*)d_in[6];
    const float* proj_b      = (const float*)d_in[7];
    const float* res_W0      = (const float*)d_in[8];
    const float* res_b0      = (const float*)d_in[9];
    const float* res_W1      = (const float*)d_in[10];
    const float* res_b1      = (const float*)d_in[11];
    const float* layers_W    = (const float*)d_in[12];
    const float* layers_b    = (const float*)d_in[13];
    const float* channels    = (const float*)d_in[14];
    const float* out_W       = (const float*)d_in[15];
    const float* out_b       = (const float*)d_in[16];

    char* ws = (char*)d_ws;
    float* feats            = (float*)(ws + OFF_FEATS);
    unsigned short* projWT  = (unsigned short*)(ws + OFF_PROJWT);
    unsigned short* res0WT  = (unsigned short*)(ws + OFF_RES0WT);
    unsigned short* res1WT  = (unsigned short*)(ws + OFF_RES1WT);
    unsigned short* layWT   = (unsigned short*)(ws + OFF_LAYWT);
    unsigned short* myin    = (unsigned short*)(ws + OFF_MYIN);
    unsigned short* R0      = (unsigned short*)(ws + OFF_R0);
    unsigned short* Rb      = (unsigned short*)(ws + OFF_R);
    unsigned short* A0      = (unsigned short*)(ws + OFF_A0);
    unsigned short* A1      = (unsigned short*)(ws + OFF_A1);
    float* partial          = (float*)(ws + OFF_A0);   // reused before A0 is written

    // weights -> transposed/padded bf16
    wconv_k<<<(512 * 256 + 255) / 256, 256, 0, stream>>>(proj_W, projWT, CATCH, CATPAD, IC, 512 * 256);
    wconv_k<<<(512 * 256 + 255) / 256, 256, 0, stream>>>(res_W0, res0WT, CATCH, CATPAD, IC, 512 * 256);
    wconv_k<<<(512 * 512 + 255) / 256, 256, 0, stream>>>(res_W1, res1WT, IC, IC, IC, 512 * 512);
    wconv_k<<<(6 * 512 * 512 + 255) / 256, 256, 0, stream>>>(layers_W, layWT, IC, IC, IC, 6 * 512 * 512);

    feats_part_k<<<dim3(16, NSLICE), 256, 0, stream>>>(grid_xy, xy_offset, bandwidths, grid_0, sound_loc, partial);
    feats_reduce_k<<<16, 128, 0, stream>>>(partial, feats);
    build_k<<<MROWS, 256, 0, stream>>>(feats, input_stuff, myin);

    // 1D grids (swizzled in-kernel): 125*4=500 for M=16000, 500*4=2000 for M=64000
    // proj (+channels[0], leaky, expand x4) -> A0
    gemm_k<0><<<500, 256, 0, stream>>>(myin, projWT, A0, CATPAD, proj_b, channels, nullptr);
    // residual branch
    gemm_k<4><<<500, 256, 0, stream>>>(myin, res0WT, R0, CATPAD, res_b0, nullptr, nullptr);
    gemm_k<5><<<500, 256, 0, stream>>>(R0, res1WT, Rb, IC, res_b1, nullptr, nullptr);
    // 6 layers, ping-pong A0/A1; residual added at k==2; k==5 last (no leaky)
    gemm_k<1><<<2000, 256, 0, stream>>>(A0, layWT + 0 * 262144, A1, IC, layers_b + 0 * 512, channels + 1 * 2048, nullptr);
    gemm_k<1><<<2000, 256, 0, stream>>>(A1, layWT + 1 * 262144, A0, IC, layers_b + 1 * 512, channels + 2 * 2048, nullptr);
    gemm_k<2><<<2000, 256, 0, stream>>>(A0, layWT + 2 * 262144, A1, IC, layers_b + 2 * 512, channels + 3 * 2048, Rb);
    gemm_k<1><<<2000, 256, 0, stream>>>(A1, layWT + 3 * 262144, A0, IC, layers_b + 3 * 512, channels + 4 * 2048, nullptr);
    gemm_k<1><<<2000, 256, 0, stream>>>(A0, layWT + 4 * 262144, A1, IC, layers_b + 4 * 512, channels + 5 * 2048, nullptr);
    gemm_k<3><<<2000, 256, 0, stream>>>(A1, layWT + 5 * 262144, A0, IC, layers_b + 5 * 512, channels + 6 * 2048, nullptr);

    final_k<<<MROWS, 256, 0, stream>>>(A0, out_W, out_b, (float*)d_out);
}